// Round 3
// baseline (1892.706 us; speedup 1.0000x reference)
//
#include <hip/hip_runtime.h>

typedef unsigned short u16;
typedef unsigned int u32;

typedef __attribute__((ext_vector_type(8))) short bf16x8;
typedef __attribute__((ext_vector_type(4))) float f32x4;

// ---------- helpers ----------
__device__ __forceinline__ float bf2f(u16 v) {
    union { u32 i; float f; } u; u.i = ((u32)v) << 16; return u.f;
}
__device__ __forceinline__ u16 f2bf(float f) {
    union { float f; u32 i; } u; u.f = f;
    u32 r = u.i + 0x7FFFu + ((u.i >> 16) & 1u);   // RNE
    return (u16)(r >> 16);
}
__device__ __forceinline__ u32 pack2(float lo, float hi) {
    return (u32)f2bf(lo) | ((u32)f2bf(hi) << 16);
}
__device__ __forceinline__ void unpack8(uint4 r, float* o) {
    o[0] = __uint_as_float(r.x << 16); o[1] = __uint_as_float(r.x & 0xffff0000u);
    o[2] = __uint_as_float(r.y << 16); o[3] = __uint_as_float(r.y & 0xffff0000u);
    o[4] = __uint_as_float(r.z << 16); o[5] = __uint_as_float(r.z & 0xffff0000u);
    o[6] = __uint_as_float(r.w << 16); o[7] = __uint_as_float(r.w & 0xffff0000u);
}

// ---------- GEMM: C(MxN) = A(MxK,row) * B(KxN,row), fp32 acc ----------
// AF/BF/CF: 1 = that matrix is fp32 in memory (converted to/from bf16 here), 0 = bf16.
// 128x128 tile, BK=32, 4 waves each 64x64 (4x4 of 16x16x32 MFMA).
template<int AF, int BF, int CF>
__global__ __launch_bounds__(256) void gemm_t(const void* __restrict__ Ap,
                                              const void* __restrict__ Bp,
                                              void* __restrict__ Cp,
                                              int M, int N, int K)
{
    constexpr int LDH = 56;  // halves; 112B row stride -> 16B aligned, 2-way bank alias only
    __shared__ __align__(16) u16 As[128 * LDH];
    __shared__ __align__(16) u16 Bs[128 * LDH];

    const int tid = threadIdx.x;
    const int lane = tid & 63;
    const int wave = tid >> 6;
    const int wm = (wave >> 1) * 64;
    const int wn = (wave & 1) * 64;
    const int lanelo = lane & 15;
    const int quad = lane >> 4;
    const long m0 = (long)blockIdx.y * 128;
    const long n0 = (long)blockIdx.x * 128;

    f32x4 acc[4][4];
#pragma unroll
    for (int i = 0; i < 4; ++i)
#pragma unroll
        for (int j = 0; j < 4; ++j) acc[i][j] = (f32x4)0.0f;

    const int arow = tid >> 2;          // 0..63 (+64 second pass)
    const int aoff = (tid & 3) * 8;
    const int bn = tid & 127;           // B staging column
    const int kg0 = tid >> 7;           // 0/1 (+2 second pass)

    for (int k0 = 0; k0 < K; k0 += 32) {
        uint4 a0, a1;
        if constexpr (AF) {
            const float* A = (const float*)Ap;
            const float* p0 = &A[(m0 + arow) * (long)K + k0 + aoff];
            const float* p1 = &A[(m0 + arow + 64) * (long)K + k0 + aoff];
            float4 x0 = *(const float4*)p0, x1 = *(const float4*)(p0 + 4);
            float4 y0 = *(const float4*)p1, y1 = *(const float4*)(p1 + 4);
            a0 = make_uint4(pack2(x0.x, x0.y), pack2(x0.z, x0.w), pack2(x1.x, x1.y), pack2(x1.z, x1.w));
            a1 = make_uint4(pack2(y0.x, y0.y), pack2(y0.z, y0.w), pack2(y1.x, y1.y), pack2(y1.z, y1.w));
        } else {
            const u16* A = (const u16*)Ap;
            a0 = *(const uint4*)&A[(m0 + arow) * (long)K + k0 + aoff];
            a1 = *(const uint4*)&A[(m0 + arow + 64) * (long)K + k0 + aoff];
        }
        // B: coalesced row reads, transpose into Bs
        u16 bv0[8], bv1[8];
        if constexpr (BF) {
            const float* B = (const float*)Bp;
            const float* bp0 = &B[(long)(k0 + kg0 * 8) * N + n0 + bn];
            const float* bp1 = &B[(long)(k0 + (kg0 + 2) * 8) * N + n0 + bn];
#pragma unroll
            for (int j = 0; j < 8; ++j) bv0[j] = f2bf(bp0[(long)j * N]);
#pragma unroll
            for (int j = 0; j < 8; ++j) bv1[j] = f2bf(bp1[(long)j * N]);
        } else {
            const u16* B = (const u16*)Bp;
            const u16* bp0 = &B[(long)(k0 + kg0 * 8) * N + n0 + bn];
            const u16* bp1 = &B[(long)(k0 + (kg0 + 2) * 8) * N + n0 + bn];
#pragma unroll
            for (int j = 0; j < 8; ++j) bv0[j] = bp0[(long)j * N];
#pragma unroll
            for (int j = 0; j < 8; ++j) bv1[j] = bp1[(long)j * N];
        }

        __syncthreads();
        *(uint4*)&As[arow * LDH + aoff] = a0;
        *(uint4*)&As[(arow + 64) * LDH + aoff] = a1;
        uint4 p0, p1;
        p0.x = (u32)bv0[0] | ((u32)bv0[1] << 16);
        p0.y = (u32)bv0[2] | ((u32)bv0[3] << 16);
        p0.z = (u32)bv0[4] | ((u32)bv0[5] << 16);
        p0.w = (u32)bv0[6] | ((u32)bv0[7] << 16);
        p1.x = (u32)bv1[0] | ((u32)bv1[1] << 16);
        p1.y = (u32)bv1[2] | ((u32)bv1[3] << 16);
        p1.z = (u32)bv1[4] | ((u32)bv1[5] << 16);
        p1.w = (u32)bv1[6] | ((u32)bv1[7] << 16);
        *(uint4*)&Bs[bn * LDH + kg0 * 8] = p0;
        *(uint4*)&Bs[bn * LDH + (kg0 + 2) * 8] = p1;
        __syncthreads();

        bf16x8 af[4], bf[4];
#pragma unroll
        for (int mt = 0; mt < 4; ++mt)
            af[mt] = *(const bf16x8*)&As[(wm + mt * 16 + lanelo) * LDH + quad * 8];
#pragma unroll
        for (int nt = 0; nt < 4; ++nt)
            bf[nt] = *(const bf16x8*)&Bs[(wn + nt * 16 + lanelo) * LDH + quad * 8];
#pragma unroll
        for (int mt = 0; mt < 4; ++mt)
#pragma unroll
            for (int nt = 0; nt < 4; ++nt)
                acc[mt][nt] = __builtin_amdgcn_mfma_f32_16x16x32_bf16(af[mt], bf[nt], acc[mt][nt], 0, 0, 0);
    }

#pragma unroll
    for (int mt = 0; mt < 4; ++mt)
#pragma unroll
        for (int nt = 0; nt < 4; ++nt)
#pragma unroll
            for (int r = 0; r < 4; ++r) {
                long row = m0 + wm + mt * 16 + quad * 4 + r;
                long col = n0 + wn + nt * 16 + lanelo;
                if constexpr (CF) ((float*)Cp)[row * N + col] = acc[mt][nt][r];
                else              ((u16*)Cp)[row * N + col] = f2bf(acc[mt][nt][r]);
            }
}

// ---------- ba = hs @ w_ba (2048x64) with g/beta epilogue ----------
__global__ __launch_bounds__(256) void ba_kernel(const float* __restrict__ hs,
                                                 const float* __restrict__ wba,
                                                 const float* __restrict__ A_log,
                                                 const float* __restrict__ dt_bias,
                                                 float* __restrict__ gbuf,
                                                 float* __restrict__ bbuf)
{
    const int m = blockIdx.x * 4 + (threadIdx.x >> 6);
    const int n = threadIdx.x & 63;
    const float* hrow = &hs[(long)m * 2048];
    float acc = 0.f;
#pragma unroll 8
    for (int k = 0; k < 2048; ++k)
        acc += hrow[k] * wba[(long)k * 64 + n];
    const int hk4 = n >> 2, r = n & 3;
    if (r < 2) {
        bbuf[(long)m * 32 + hk4 * 2 + r] = 1.f / (1.f + expf(-acc));
    } else {
        const int hv = hk4 * 2 + (r - 2);
        float x = acc + dt_bias[hv];
        float sp = (x > 20.f) ? x : log1pf(expf(x));
        gbuf[(long)m * 32 + hv] = -expf(A_log[hv]) * sp;
    }
}

// ---------- causal depthwise conv (K=4) + silu + per-head l2norm ----------
__global__ __launch_bounds__(128) void conv_kernel(const u16* __restrict__ qkvz,
                                                   const float* __restrict__ cw,
                                                   u16* __restrict__ out)
{
    const int bid = blockIdx.x;          // bs*64 + grp
    const int bs = bid >> 6, grp = bid & 63;
    const int tidx = threadIdx.x;        // 128
    const int c = grp * 128 + tidx;
    int n;
    if (c < 2048)       n = (c >> 7) * 768 + (c & 127);
    else if (c < 4096) { int c2 = c - 2048; n = (c2 >> 7) * 768 + 128 + (c2 & 127); }
    else               { int c2 = c - 4096; n = (c2 >> 8) * 768 + 256 + (c2 & 255); }
    const int s = bs & 2047;

    float4 w = *(const float4*)&cw[c * 4];

    const long base = (long)bs * 12288 + n;
    float acc = 0.f;
    if (s >= 3) acc += bf2f(qkvz[base - 3 * 12288]) * w.x;
    if (s >= 2) acc += bf2f(qkvz[base - 2 * 12288]) * w.y;
    if (s >= 1) acc += bf2f(qkvz[base - 1 * 12288]) * w.z;
    acc += bf2f(qkvz[base]) * w.w;
    float val = acc / (1.f + expf(-acc));   // silu

    if (grp < 32) {  // q or k head: l2norm over these 128 threads
        __shared__ float red[2];
        float ss = val * val;
        ss += __shfl_xor(ss, 1);  ss += __shfl_xor(ss, 2);  ss += __shfl_xor(ss, 4);
        ss += __shfl_xor(ss, 8);  ss += __shfl_xor(ss, 16); ss += __shfl_xor(ss, 32);
        if ((tidx & 63) == 0) red[tidx >> 6] = ss;
        __syncthreads();
        val *= rsqrtf(red[0] + red[1] + 1e-6f);
    }
    out[(long)bs * 8192 + c] = f2bf(val);
}

// ---------- sequential gated delta scan ----------
// grid 256 = (b, h, quarter); 256 threads; lane: rg=lane&7 (16 rows each), cl=lane>>3;
// col = qtr*32 + wave*8 + cl. State S[16] fp32 in VGPRs.
__global__ __launch_bounds__(256) void scan_kernel(const u16* __restrict__ conv,
                                                   const float* __restrict__ gbuf,
                                                   const float* __restrict__ bbuf,
                                                   u16* __restrict__ obuf)
{
    __shared__ float lk[32 * 128];
    __shared__ float lq[32 * 128];
    __shared__ float lv[32 * 32];
    __shared__ float leg[32];
    __shared__ float lbe[32];

    const int bid = blockIdx.x;
    const int b = bid >> 7;
    const int h = (bid >> 2) & 31;
    const int qtr = bid & 3;
    const int hk = h >> 1;
    const int tid = threadIdx.x;
    const int lane = tid & 63;
    const int wave = tid >> 6;
    const int rg = lane & 7;
    const int cl = lane >> 3;
    const int col = qtr * 32 + wave * 8 + cl;
    const long rowbase = (long)b * 2048;
    const float scale = 0.08838834764831845f;  // 128^-0.5

    float S[16];
#pragma unroll
    for (int i = 0; i < 16; ++i) S[i] = 0.f;

    for (int t0 = 0; t0 < 2048; t0 += 32) {
        __syncthreads();
        // stage q,k: 32 steps x 128 floats each
#pragma unroll
        for (int p = 0; p < 2; ++p) {
            const int id = tid + p * 256;
            const int tt = id >> 4, r8 = (id & 15) * 8;
            const long base = (rowbase + t0 + tt) * 8192;
            uint4 qraw = *(const uint4*)&conv[base + hk * 128 + r8];
            uint4 kraw = *(const uint4*)&conv[base + 2048 + hk * 128 + r8];
            float t8[8];
            unpack8(qraw, t8);
#pragma unroll
            for (int i = 0; i < 8; ++i) lq[tt * 128 + r8 + i] = t8[i];
            unpack8(kraw, t8);
#pragma unroll
            for (int i = 0; i < 8; ++i) lk[tt * 128 + r8 + i] = t8[i];
        }
        if (tid < 128) {
            const int tt = tid >> 2, c8 = (tid & 3) * 8;
            uint4 vraw = *(const uint4*)&conv[(rowbase + t0 + tt) * 8192 + 4096 + h * 128 + qtr * 32 + c8];
            float t8[8];
            unpack8(vraw, t8);
#pragma unroll
            for (int i = 0; i < 8; ++i) lv[tt * 32 + c8 + i] = t8[i];
        }
        if (tid < 32) {
            leg[tid] = expf(gbuf[(rowbase + t0 + tid) * 32 + h]);
            lbe[tid] = bbuf[(rowbase + t0 + tid) * 32 + h];
        }
        __syncthreads();

#pragma unroll 4
        for (int tt = 0; tt < 32; ++tt) {
            const float eg = leg[tt];
            const float be = lbe[tt];
            const float vv = lv[tt * 32 + wave * 8 + cl];
            const float4* kp = (const float4*)&lk[tt * 128 + rg * 16];
            const float4* qp = (const float4*)&lq[tt * 128 + rg * 16];
            float kr[16], qr[16];
#pragma unroll
            for (int i = 0; i < 4; ++i) {
                float4 a = kp[i];
                kr[4 * i] = a.x; kr[4 * i + 1] = a.y; kr[4 * i + 2] = a.z; kr[4 * i + 3] = a.w;
                float4 bq = qp[i];
                qr[4 * i] = bq.x; qr[4 * i + 1] = bq.y; qr[4 * i + 2] = bq.z; qr[4 * i + 3] = bq.w;
            }
            float pp = 0.f;
#pragma unroll
            for (int r = 0; r < 16; ++r) pp += kr[r] * S[r];
            pp += __shfl_xor(pp, 1);
            pp += __shfl_xor(pp, 2);
            pp += __shfl_xor(pp, 4);
            const float delta = be * (vv - pp * eg);
            float oo = 0.f;
#pragma unroll
            for (int r = 0; r < 16; ++r) {
                S[r] = S[r] * eg + kr[r] * delta;
                oo += qr[r] * S[r];
            }
            oo += __shfl_xor(oo, 1);
            oo += __shfl_xor(oo, 2);
            oo += __shfl_xor(oo, 4);
            if (rg == 0)
                obuf[((rowbase + t0 + tt) * 32 + h) * 128 + col] = f2bf(oo * scale);
        }
    }
}

// ---------- RMS-norm + gating: y = o*rsqrt(mean(o^2)+eps) * norm_w * silu(z) ----------
__global__ __launch_bounds__(128) void gate_kernel(const u16* __restrict__ obuf,
                                                   const u16* __restrict__ qkvz,
                                                   const float* __restrict__ norm_w,
                                                   u16* __restrict__ ybuf)
{
    const int bid = blockIdx.x;          // bs*32 + hv
    const int bs = bid >> 5, hv = bid & 31;
    const int dv = threadIdx.x;
    __shared__ float red[2];
    float v = bf2f(obuf[(long)bid * 128 + dv]);
    float ss = v * v;
    ss += __shfl_xor(ss, 1);  ss += __shfl_xor(ss, 2);  ss += __shfl_xor(ss, 4);
    ss += __shfl_xor(ss, 8);  ss += __shfl_xor(ss, 16); ss += __shfl_xor(ss, 32);
    if ((dv & 63) == 0) red[dv >> 6] = ss;
    __syncthreads();
    const float mean = (red[0] + red[1]) * (1.f / 128.f);
    const float rstd = rsqrtf(mean + 1e-6f);
    const int hk = hv >> 1;
    const float z = bf2f(qkvz[(long)bs * 12288 + hk * 768 + 512 + (hv & 1) * 128 + dv]);
    const float y = v * rstd * norm_w[dv] * (z / (1.f + expf(-z)));
    ybuf[(long)bs * 4096 + hv * 128 + dv] = f2bf(y);
}

// ---------- launch ----------
extern "C" void kernel_launch(void* const* d_in, const int* in_sizes, int n_in,
                              void* d_out, int out_size, void* d_ws, size_t ws_size,
                              hipStream_t stream)
{
    const float* hs      = (const float*)d_in[0];
    const float* w_qkvz  = (const float*)d_in[1];
    const float* w_ba    = (const float*)d_in[2];
    const float* conv_w  = (const float*)d_in[3];
    const float* A_log   = (const float*)d_in[4];
    const float* dt_bias = (const float*)d_in[5];
    const float* norm_w  = (const float*)d_in[6];
    const float* w_out   = (const float*)d_in[7];

    char* ws = (char*)d_ws;
    u16*   qkvz  = (u16*)ws;                                   // 4096*12288*2 = 100,663,296
    u16*   convb = (u16*)(ws + 100663296);                     // 4096*8192*2  =  67,108,864
    float* gbuf  = (float*)(ws + 100663296 + 67108864);        // 4096*32*4    =     524,288
    float* bbuf  = gbuf + 4096 * 32;                           //                     524,288
    u16*   obuf  = (u16*)(bbuf + 4096 * 32);                   // 4096*32*128*2=  33,554,432
    u16*   ybuf  = convb;  // alias: conv output dead after scan; gate reads only obuf/qkvz

    // 1) qkvz = hs @ w_qkvz   (4096 x 2048 x 12288), fp32 in -> bf16 out
    gemm_t<1, 1, 0><<<dim3(96, 32), 256, 0, stream>>>(hs, w_qkvz, qkvz, 4096, 12288, 2048);
    // 2) g/beta from hs @ w_ba
    ba_kernel<<<1024, 256, 0, stream>>>(hs, w_ba, A_log, dt_bias, gbuf, bbuf);
    // 3) conv + silu + l2norm(q,k)
    conv_kernel<<<4096 * 64, 128, 0, stream>>>(qkvz, conv_w, convb);
    // 4) gated delta scan
    scan_kernel<<<256, 256, 0, stream>>>(convb, gbuf, bbuf, obuf);
    // 5) gating
    gate_kernel<<<4096 * 32, 128, 0, stream>>>(obuf, qkvz, norm_w, ybuf);
    // 6) out = y @ w_out  (4096 x 4096 x 2048), bf16 A, fp32 B -> fp32 out
    gemm_t<0, 1, 1><<<dim3(16, 32), 256, 0, stream>>>(ybuf, w_out, d_out, 4096, 2048, 4096);
}

// Round 5
// 1655.468 us; speedup vs baseline: 1.1433x; 1.1433x over previous
//
#include <hip/hip_runtime.h>

typedef unsigned short u16;
typedef unsigned int u32;

typedef __attribute__((ext_vector_type(8))) short bf16x8;
typedef __attribute__((ext_vector_type(4))) float f32x4;

// ---------- helpers ----------
__device__ __forceinline__ float bf2f(u16 v) {
    union { u32 i; float f; } u; u.i = ((u32)v) << 16; return u.f;
}
__device__ __forceinline__ u16 f2bf(float f) {
    union { float f; u32 i; } u; u.f = f;
    u32 r = u.i + 0x7FFFu + ((u.i >> 16) & 1u);   // RNE
    return (u16)(r >> 16);
}
__device__ __forceinline__ u32 pack2(float lo, float hi) {
    return (u32)f2bf(lo) | ((u32)f2bf(hi) << 16);
}
__device__ __forceinline__ void unpack8(uint4 r, float* o) {
    o[0] = __uint_as_float(r.x << 16); o[1] = __uint_as_float(r.x & 0xffff0000u);
    o[2] = __uint_as_float(r.y << 16); o[3] = __uint_as_float(r.y & 0xffff0000u);
    o[4] = __uint_as_float(r.z << 16); o[5] = __uint_as_float(r.z & 0xffff0000u);
    o[6] = __uint_as_float(r.w << 16); o[7] = __uint_as_float(r.w & 0xffff0000u);
}
__device__ __forceinline__ void async16(const void* g, void* l) {
    __builtin_amdgcn_global_load_lds((const __attribute__((address_space(1))) void*)g,
                                     (__attribute__((address_space(3))) void*)l, 16, 0, 0);
}
__device__ __forceinline__ void load8(float* d, const float* s) {
    float4 a = *(const float4*)s, b = *(const float4*)(s + 4);
    d[0] = a.x; d[1] = a.y; d[2] = a.z; d[3] = a.w;
    d[4] = b.x; d[5] = b.y; d[6] = b.z; d[7] = b.w;
}

// ---------- fp32 -> bf16 convert (elementwise, 8/thread) ----------
__global__ __launch_bounds__(256) void f2b_kernel(const float* __restrict__ in,
                                                  u16* __restrict__ out)
{
    long i = ((long)blockIdx.x * 256 + threadIdx.x) * 8;
    float4 a = *(const float4*)&in[i], b = *(const float4*)&in[i + 4];
    uint4 o = make_uint4(pack2(a.x, a.y), pack2(a.z, a.w), pack2(b.x, b.y), pack2(b.z, b.w));
    *(uint4*)&out[i] = o;
}

// ---------- fp32 RxC -> bf16 CxR transpose ----------
__global__ __launch_bounds__(256) void transpose_f2b(const float* __restrict__ in,
                                                     u16* __restrict__ out, int R, int C)
{
    __shared__ float tile[32][33];
    const int r0 = blockIdx.y * 32, c0 = blockIdx.x * 32;
    const int tr = threadIdx.x >> 3;
    const int tc = (threadIdx.x & 7) * 4;
    float4 v = *(const float4*)&in[(long)(r0 + tr) * C + c0 + tc];
    tile[tr][tc] = v.x; tile[tr][tc + 1] = v.y; tile[tr][tc + 2] = v.z; tile[tr][tc + 3] = v.w;
    __syncthreads();
    uint2 o;
    o.x = pack2(tile[tc][tr], tile[tc + 1][tr]);
    o.y = pack2(tile[tc + 2][tr], tile[tc + 3][tr]);
    *(uint2*)&out[(long)(c0 + tr) * R + r0 + tc] = o;
}

// ---------- GEMM (m97-style): C(MxN) = A(MxK) * Bt(NxK)^T, bf16 in, fp32 acc ----------
// global_load_lds width-16 staging; 128x128 tile, BK=32; 4 waves x (4x4) 16x16x32 MFMA.
template<int CF>   // CF=1: C fp32, CF=0: C bf16
__global__ __launch_bounds__(256) void gemm_bt(const u16* __restrict__ A,
                                               const u16* __restrict__ Bt,
                                               void* __restrict__ Cp,
                                               int M, int N, int K)
{
    __shared__ __align__(16) u16 As[128 * 32];
    __shared__ __align__(16) u16 Bs[128 * 32];

    const int tid = threadIdx.x;
    const int lane = tid & 63;
    const int wave = tid >> 6;
    const int wm = (wave >> 1) * 64;
    const int wn = (wave & 1) * 64;
    const int lanelo = lane & 15;
    const int quad = lane >> 4;
    const long m0 = (long)blockIdx.y * 128;
    const long n0 = (long)blockIdx.x * 128;

    f32x4 acc[4][4];
#pragma unroll
    for (int i = 0; i < 4; ++i)
#pragma unroll
        for (int j = 0; j < 4; ++j) acc[i][j] = (f32x4)0.0f;

    // staging: wave w covers rows w*16..+15 and w*16+64..+79; lane l -> row +l/4, k-chunk (l&3)*8
    const u16* agp0 = A + (long)(m0 + wave * 16 + (lane >> 2)) * K + (lane & 3) * 8;
    const u16* agp1 = agp0 + 64 * (long)K;
    const u16* bgp0 = Bt + (long)(n0 + wave * 16 + (lane >> 2)) * K + (lane & 3) * 8;
    const u16* bgp1 = bgp0 + 64 * (long)K;
    u16* lA0 = &As[wave * 16 * 32];
    u16* lA1 = &As[(wave * 16 + 64) * 32];
    u16* lB0 = &Bs[wave * 16 * 32];
    u16* lB1 = &Bs[(wave * 16 + 64) * 32];

    for (int k0 = 0; k0 < K; k0 += 32) {
        __syncthreads();
        async16(agp0 + k0, lA0);
        async16(agp1 + k0, lA1);
        async16(bgp0 + k0, lB0);
        async16(bgp1 + k0, lB1);
        __syncthreads();

        bf16x8 af[4], bf[4];
#pragma unroll
        for (int mt = 0; mt < 4; ++mt)
            af[mt] = *(const bf16x8*)&As[(wm + mt * 16 + lanelo) * 32 + quad * 8];
#pragma unroll
        for (int nt = 0; nt < 4; ++nt)
            bf[nt] = *(const bf16x8*)&Bs[(wn + nt * 16 + lanelo) * 32 + quad * 8];
#pragma unroll
        for (int mt = 0; mt < 4; ++mt)
#pragma unroll
            for (int nt = 0; nt < 4; ++nt)
                acc[mt][nt] = __builtin_amdgcn_mfma_f32_16x16x32_bf16(af[mt], bf[nt], acc[mt][nt], 0, 0, 0);
    }

#pragma unroll
    for (int mt = 0; mt < 4; ++mt)
#pragma unroll
        for (int nt = 0; nt < 4; ++nt)
#pragma unroll
            for (int r = 0; r < 4; ++r) {
                long row = m0 + wm + mt * 16 + quad * 4 + r;
                long col = n0 + wn + nt * 16 + lanelo;
                if constexpr (CF) ((float*)Cp)[row * N + col] = acc[mt][nt][r];
                else              ((u16*)Cp)[row * N + col] = f2bf(acc[mt][nt][r]);
            }
}

// ---------- ba = hs @ w_ba (2048x64) with g/beta epilogue ----------
__global__ __launch_bounds__(256) void ba_kernel(const float* __restrict__ hs,
                                                 const float* __restrict__ wba,
                                                 const float* __restrict__ A_log,
                                                 const float* __restrict__ dt_bias,
                                                 float* __restrict__ gbuf,
                                                 float* __restrict__ bbuf)
{
    const int m = blockIdx.x * 4 + (threadIdx.x >> 6);
    const int n = threadIdx.x & 63;
    const float* hrow = &hs[(long)m * 2048];
    float acc = 0.f;
#pragma unroll 8
    for (int k = 0; k < 2048; ++k)
        acc += hrow[k] * wba[(long)k * 64 + n];
    const int hk4 = n >> 2, r = n & 3;
    if (r < 2) {
        bbuf[(long)m * 32 + hk4 * 2 + r] = 1.f / (1.f + expf(-acc));
    } else {
        const int hv = hk4 * 2 + (r - 2);
        float x = acc + dt_bias[hv];
        float sp = (x > 20.f) ? x : log1pf(expf(x));
        gbuf[(long)m * 32 + hv] = -expf(A_log[hv]) * sp;
    }
}

// ---------- causal depthwise conv (K=4) + silu + per-head l2norm, 8 ch/thread ----------
__global__ __launch_bounds__(256) void conv_kernel(const u16* __restrict__ qkvz,
                                                   const float* __restrict__ cw,
                                                   u16* __restrict__ out)
{
    const int bid = blockIdx.x;          // bs*4 + part
    const int bs = bid >> 2, part = bid & 3;
    const int c = part * 2048 + threadIdx.x * 8;
    int n;
    if (c < 2048)       n = (c >> 7) * 768 + (c & 127);
    else if (c < 4096) { int c2 = c - 2048; n = (c2 >> 7) * 768 + 128 + (c2 & 127); }
    else               { int c2 = c - 4096; n = (c2 >> 8) * 768 + 256 + (c2 & 255); }
    const int s = bs & 2047;
    const long base = (long)bs * 12288 + n;

    float x0[8], x1[8], x2[8], x3[8];
#pragma unroll
    for (int i = 0; i < 8; ++i) { x0[i] = 0.f; x1[i] = 0.f; x2[i] = 0.f; }
    { uint4 r = *(const uint4*)&qkvz[base]; unpack8(r, x3); }
    if (s >= 1) { uint4 r = *(const uint4*)&qkvz[base - 12288];     unpack8(r, x2); }
    if (s >= 2) { uint4 r = *(const uint4*)&qkvz[base - 2 * 12288]; unpack8(r, x1); }
    if (s >= 3) { uint4 r = *(const uint4*)&qkvz[base - 3 * 12288]; unpack8(r, x0); }

    float v[8]; float ss = 0.f;
#pragma unroll
    for (int i = 0; i < 8; ++i) {
        float4 w = *(const float4*)&cw[(c + i) * 4];
        float a = x0[i] * w.x + x1[i] * w.y + x2[i] * w.z + x3[i] * w.w;
        v[i] = a / (1.f + expf(-a));
        ss += v[i] * v[i];
    }
    if (part < 2) {   // q/k: l2norm over 128-ch head = 16 consecutive lanes
        ss += __shfl_xor(ss, 1); ss += __shfl_xor(ss, 2);
        ss += __shfl_xor(ss, 4); ss += __shfl_xor(ss, 8);
        float rn = rsqrtf(ss + 1e-6f);
#pragma unroll
        for (int i = 0; i < 8; ++i) v[i] *= rn;
    }
    uint4 o = make_uint4(pack2(v[0], v[1]), pack2(v[2], v[3]), pack2(v[4], v[5]), pack2(v[6], v[7]));
    *(uint4*)&out[(long)bs * 8192 + c] = o;
}

// ---------- sequential gated delta scan ----------
// grid 512 = (b, h, col-block of 16); 256 threads; lane: rg=lane&15 (8 rows each),
// cloc=wave*4+(lane>>4). State S[8] fp32 in VGPRs; k/q/v/g/b prefetched 1 step ahead.
__global__ __launch_bounds__(256) void scan_kernel(const u16* __restrict__ conv,
                                                   const float* __restrict__ gbuf,
                                                   const float* __restrict__ bbuf,
                                                   u16* __restrict__ obuf)
{
    __shared__ float lk[32 * 128];
    __shared__ float lq[32 * 128];
    __shared__ float lv[32 * 16];
    __shared__ float leg[32];
    __shared__ float lbe[32];

    const int bid = blockIdx.x;
    const int b = bid >> 8;
    const int h = (bid >> 3) & 31;
    const int cb = bid & 7;
    const int c0 = cb * 16;
    const int hk = h >> 1;
    const int tid = threadIdx.x;
    const int lane = tid & 63;
    const int wave = tid >> 6;
    const int rg = lane & 15;
    const int cloc = wave * 4 + (lane >> 4);
    const long rowbase = (long)b * 2048;
    const float scale = 0.08838834764831845f;  // 128^-0.5

    float S[8];
#pragma unroll
    for (int i = 0; i < 8; ++i) S[i] = 0.f;

    for (int t0 = 0; t0 < 2048; t0 += 32) {
        __syncthreads();
#pragma unroll
        for (int p = 0; p < 2; ++p) {
            const int id = tid + p * 256;
            const int tt = id >> 4, r8 = (id & 15) * 8;
            const long base = (rowbase + t0 + tt) * 8192;
            uint4 qraw = *(const uint4*)&conv[base + hk * 128 + r8];
            uint4 kraw = *(const uint4*)&conv[base + 2048 + hk * 128 + r8];
            float t8[8];
            unpack8(qraw, t8);
#pragma unroll
            for (int i = 0; i < 8; ++i) lq[tt * 128 + r8 + i] = t8[i];
            unpack8(kraw, t8);
#pragma unroll
            for (int i = 0; i < 8; ++i) lk[tt * 128 + r8 + i] = t8[i];
        }
        if (tid < 64) {
            const int tt = tid >> 1, c8 = (tid & 1) * 8;
            uint4 vraw = *(const uint4*)&conv[(rowbase + t0 + tt) * 8192 + 4096 + h * 128 + c0 + c8];
            float t8[8];
            unpack8(vraw, t8);
#pragma unroll
            for (int i = 0; i < 8; ++i) lv[tt * 16 + c8 + i] = t8[i];
        }
        if (tid < 32) {
            leg[tid] = expf(gbuf[(rowbase + t0 + tid) * 32 + h]);
            lbe[tid] = bbuf[(rowbase + t0 + tid) * 32 + h];
        }
        __syncthreads();

        float kr[2][8], qr[2][8], vvp[2], egp[2], bep[2];
        load8(kr[0], &lk[rg * 8]);
        load8(qr[0], &lq[rg * 8]);
        vvp[0] = lv[cloc]; egp[0] = leg[0]; bep[0] = lbe[0];
#pragma unroll
        for (int tt = 0; tt < 32; ++tt) {
            const int cur = tt & 1, nxt = cur ^ 1;
            if (tt < 31) {  // prefetch t+1 while computing t
                load8(kr[nxt], &lk[(tt + 1) * 128 + rg * 8]);
                load8(qr[nxt], &lq[(tt + 1) * 128 + rg * 8]);
                vvp[nxt] = lv[(tt + 1) * 16 + cloc];
                egp[nxt] = leg[tt + 1];
                bep[nxt] = lbe[tt + 1];
            }
            const float eg = egp[cur], be = bep[cur], vv = vvp[cur];
            const float* k8 = kr[cur];
            const float* q8 = qr[cur];
            float pp0 = k8[0] * S[0];
            pp0 = fmaf(k8[2], S[2], pp0); pp0 = fmaf(k8[4], S[4], pp0); pp0 = fmaf(k8[6], S[6], pp0);
            float pp1 = k8[1] * S[1];
            pp1 = fmaf(k8[3], S[3], pp1); pp1 = fmaf(k8[5], S[5], pp1); pp1 = fmaf(k8[7], S[7], pp1);
            float pp = pp0 + pp1;
            pp += __shfl_xor(pp, 1); pp += __shfl_xor(pp, 2);
            pp += __shfl_xor(pp, 4); pp += __shfl_xor(pp, 8);
            const float delta = be * (vv - pp * eg);
#pragma unroll
            for (int r = 0; r < 8; ++r) {
                float t = k8[r] * delta;
                S[r] = fmaf(S[r], eg, t);
            }
            float oo0 = q8[0] * S[0];
            oo0 = fmaf(q8[2], S[2], oo0); oo0 = fmaf(q8[4], S[4], oo0); oo0 = fmaf(q8[6], S[6], oo0);
            float oo1 = q8[1] * S[1];
            oo1 = fmaf(q8[3], S[3], oo1); oo1 = fmaf(q8[5], S[5], oo1); oo1 = fmaf(q8[7], S[7], oo1);
            float oo = oo0 + oo1;
            oo += __shfl_xor(oo, 1); oo += __shfl_xor(oo, 2);
            oo += __shfl_xor(oo, 4); oo += __shfl_xor(oo, 8);
            if (rg == 0)
                obuf[((rowbase + t0 + tt) * 32 + h) * 128 + c0 + cloc] = f2bf(oo * scale);
        }
    }
}

// ---------- RMS-norm + gating: y = o*rsqrt(mean(o^2)+eps) * norm_w * silu(z) ----------
__global__ __launch_bounds__(128) void gate_kernel(const u16* __restrict__ obuf,
                                                   const u16* __restrict__ qkvz,
                                                   const float* __restrict__ norm_w,
                                                   u16* __restrict__ ybuf)
{
    const int bid = blockIdx.x;          // bs*32 + hv
    const int bs = bid >> 5, hv = bid & 31;
    const int dv = threadIdx.x;
    __shared__ float red[2];
    float v = bf2f(obuf[(long)bid * 128 + dv]);
    float ss = v * v;
    ss += __shfl_xor(ss, 1);  ss += __shfl_xor(ss, 2);  ss += __shfl_xor(ss, 4);
    ss += __shfl_xor(ss, 8);  ss += __shfl_xor(ss, 16); ss += __shfl_xor(ss, 32);
    if ((dv & 63) == 0) red[dv >> 6] = ss;
    __syncthreads();
    const float mean = (red[0] + red[1]) * (1.f / 128.f);
    const float rstd = rsqrtf(mean + 1e-6f);
    const int hk = hv >> 1;
    const float z = bf2f(qkvz[(long)bs * 12288 + hk * 768 + 512 + (hv & 1) * 128 + dv]);
    const float y = v * rstd * norm_w[dv] * (z / (1.f + expf(-z)));
    ybuf[(long)bs * 4096 + hv * 128 + dv] = f2bf(y);
}

// ---------- launch ----------
extern "C" void kernel_launch(void* const* d_in, const int* in_sizes, int n_in,
                              void* d_out, int out_size, void* d_ws, size_t ws_size,
                              hipStream_t stream)
{
    const float* hs      = (const float*)d_in[0];
    const float* w_qkvz  = (const float*)d_in[1];
    const float* w_ba    = (const float*)d_in[2];
    const float* conv_w  = (const float*)d_in[3];
    const float* A_log   = (const float*)d_in[4];
    const float* dt_bias = (const float*)d_in[5];
    const float* norm_w  = (const float*)d_in[6];
    const float* w_out   = (const float*)d_in[7];

    char* ws = (char*)d_ws;
    u16*   qkvz   = (u16*)ws;                          // 100,663,296 B
    u16*   convb  = (u16*)(ws + 100663296);            //  67,108,864 B
    float* gbuf   = (float*)(ws + 167772160);          //     524,288 B
    float* bbuf   = (float*)(ws + 168296448);          //     524,288 B
    char*  regE   = ws + 168820736;                    //  33,554,432 B (end 202,375,168)
    u16*   hs_b   = (u16*)regE;                        // bf16 hs (dead after GEMM1)
    u16*   obuf   = (u16*)regE;                        // overwrites hs_b at scan time
    u16*   wqkvz_t = convb;                            // bf16 w_qkvz^T (dead after GEMM1; conv overwrites)
    u16*   ybuf   = convb;                             // gate output (conv data dead after scan)
    u16*   wout_t = qkvz;                              // bf16 w_out^T (qkvz dead after gate)

    // 1) dtype prep
    f2b_kernel<<<4096, 256, 0, stream>>>(hs, hs_b);                            // 4096*2048
    transpose_f2b<<<dim3(384, 64), 256, 0, stream>>>(w_qkvz, wqkvz_t, 2048, 12288);
    // 2) qkvz = hs @ w_qkvz  (4096 x 12288 x 2048), bf16 out
    gemm_bt<0><<<dim3(96, 32), 256, 0, stream>>>(hs_b, wqkvz_t, qkvz, 4096, 12288, 2048);
    // 3) g/beta
    ba_kernel<<<1024, 256, 0, stream>>>(hs, w_ba, A_log, dt_bias, gbuf, bbuf);
    // 4) conv + silu + l2norm (overwrites wqkvz_t region)
    conv_kernel<<<4096 * 4, 256, 0, stream>>>(qkvz, conv_w, convb);
    // 5) gated delta scan (overwrites hs_b region)
    scan_kernel<<<512, 256, 0, stream>>>(convb, gbuf, bbuf, obuf);
    // 6) gating (writes ybuf = convb region)
    gate_kernel<<<4096 * 32, 128, 0, stream>>>(obuf, qkvz, norm_w, ybuf);
    // 7) w_out^T into qkvz region (dead), then out = y @ w_out (4096 x 2048 x 4096), fp32 out
    transpose_f2b<<<dim3(64, 128), 256, 0, stream>>>(w_out, wout_t, 4096, 2048);
    gemm_bt<1><<<dim3(16, 32), 256, 0, stream>>>(ybuf, wout_t, d_out, 4096, 2048, 4096);
}

// Round 6
// 1286.603 us; speedup vs baseline: 1.4711x; 1.2867x over previous
//
#include <hip/hip_runtime.h>

typedef unsigned short u16;
typedef unsigned int u32;

typedef __attribute__((ext_vector_type(8))) short bf16x8;
typedef __attribute__((ext_vector_type(4))) float f32x4;

// ---------- helpers ----------
__device__ __forceinline__ float bf2f(u16 v) {
    union { u32 i; float f; } u; u.i = ((u32)v) << 16; return u.f;
}
__device__ __forceinline__ u16 f2bf(float f) {
    union { float f; u32 i; } u; u.f = f;
    u32 r = u.i + 0x7FFFu + ((u.i >> 16) & 1u);   // RNE
    return (u16)(r >> 16);
}
__device__ __forceinline__ u32 pack2(float lo, float hi) {
    return (u32)f2bf(lo) | ((u32)f2bf(hi) << 16);
}
__device__ __forceinline__ void unpack8(uint4 r, float* o) {
    o[0] = __uint_as_float(r.x << 16); o[1] = __uint_as_float(r.x & 0xffff0000u);
    o[2] = __uint_as_float(r.y << 16); o[3] = __uint_as_float(r.y & 0xffff0000u);
    o[4] = __uint_as_float(r.z << 16); o[5] = __uint_as_float(r.z & 0xffff0000u);
    o[6] = __uint_as_float(r.w << 16); o[7] = __uint_as_float(r.w & 0xffff0000u);
}
__device__ __forceinline__ void async16(const void* g, void* l) {
    __builtin_amdgcn_global_load_lds((const __attribute__((address_space(1))) void*)g,
                                     (__attribute__((address_space(3))) void*)l, 16, 0, 0);
}
// DPP butterfly add within a row of 16 contiguous lanes (VALU-only, no LDS pipe).
template<int CTRL>
__device__ __forceinline__ float dpp_add(float x) {
    int y = __builtin_amdgcn_update_dpp(0, __float_as_int(x), CTRL, 0xf, 0xf, true);
    return x + __int_as_float(y);
}
__device__ __forceinline__ float row16_allreduce(float x) {
    x = dpp_add<0xB1>(x);    // quad_perm [1,0,3,2]  : xor 1
    x = dpp_add<0x4E>(x);    // quad_perm [2,3,0,1]  : xor 2
    x = dpp_add<0x141>(x);   // row_half_mirror      : xor 4 (at quad granularity)
    x = dpp_add<0x140>(x);   // row_mirror           : xor 8 (at half-row granularity)
    return x;
}

// ---------- fp32 -> bf16 convert (elementwise, 8/thread) ----------
__global__ __launch_bounds__(256) void f2b_kernel(const float* __restrict__ in,
                                                  u16* __restrict__ out)
{
    long i = ((long)blockIdx.x * 256 + threadIdx.x) * 8;
    float4 a = *(const float4*)&in[i], b = *(const float4*)&in[i + 4];
    uint4 o = make_uint4(pack2(a.x, a.y), pack2(a.z, a.w), pack2(b.x, b.y), pack2(b.z, b.w));
    *(uint4*)&out[i] = o;
}

// ---------- fp32 RxC -> bf16 CxR transpose ----------
__global__ __launch_bounds__(256) void transpose_f2b(const float* __restrict__ in,
                                                     u16* __restrict__ out, int R, int C)
{
    __shared__ float tile[32][33];
    const int r0 = blockIdx.y * 32, c0 = blockIdx.x * 32;
    const int tr = threadIdx.x >> 3;
    const int tc = (threadIdx.x & 7) * 4;
    float4 v = *(const float4*)&in[(long)(r0 + tr) * C + c0 + tc];
    tile[tr][tc] = v.x; tile[tr][tc + 1] = v.y; tile[tr][tc + 2] = v.z; tile[tr][tc + 3] = v.w;
    __syncthreads();
    uint2 o;
    o.x = pack2(tile[tc][tr], tile[tc + 1][tr]);
    o.y = pack2(tile[tc + 2][tr], tile[tc + 3][tr]);
    *(uint2*)&out[(long)(c0 + tr) * R + r0 + tc] = o;
}

// ---------- GEMM (m97-style): C(MxN) = A(MxK) * Bt(NxK)^T, bf16 in, fp32 acc ----------
template<int CF>   // CF=1: C fp32, CF=0: C bf16
__global__ __launch_bounds__(256) void gemm_bt(const u16* __restrict__ A,
                                               const u16* __restrict__ Bt,
                                               void* __restrict__ Cp,
                                               int M, int N, int K)
{
    __shared__ __align__(16) u16 As[128 * 32];
    __shared__ __align__(16) u16 Bs[128 * 32];

    const int tid = threadIdx.x;
    const int lane = tid & 63;
    const int wave = tid >> 6;
    const int wm = (wave >> 1) * 64;
    const int wn = (wave & 1) * 64;
    const int lanelo = lane & 15;
    const int quad = lane >> 4;
    const long m0 = (long)blockIdx.y * 128;
    const long n0 = (long)blockIdx.x * 128;

    f32x4 acc[4][4];
#pragma unroll
    for (int i = 0; i < 4; ++i)
#pragma unroll
        for (int j = 0; j < 4; ++j) acc[i][j] = (f32x4)0.0f;

    const u16* agp0 = A + (long)(m0 + wave * 16 + (lane >> 2)) * K + (lane & 3) * 8;
    const u16* agp1 = agp0 + 64 * (long)K;
    const u16* bgp0 = Bt + (long)(n0 + wave * 16 + (lane >> 2)) * K + (lane & 3) * 8;
    const u16* bgp1 = bgp0 + 64 * (long)K;
    u16* lA0 = &As[wave * 16 * 32];
    u16* lA1 = &As[(wave * 16 + 64) * 32];
    u16* lB0 = &Bs[wave * 16 * 32];
    u16* lB1 = &Bs[(wave * 16 + 64) * 32];

    for (int k0 = 0; k0 < K; k0 += 32) {
        __syncthreads();
        async16(agp0 + k0, lA0);
        async16(agp1 + k0, lA1);
        async16(bgp0 + k0, lB0);
        async16(bgp1 + k0, lB1);
        __syncthreads();

        bf16x8 af[4], bf[4];
#pragma unroll
        for (int mt = 0; mt < 4; ++mt)
            af[mt] = *(const bf16x8*)&As[(wm + mt * 16 + lanelo) * 32 + quad * 8];
#pragma unroll
        for (int nt = 0; nt < 4; ++nt)
            bf[nt] = *(const bf16x8*)&Bs[(wn + nt * 16 + lanelo) * 32 + quad * 8];
#pragma unroll
        for (int mt = 0; mt < 4; ++mt)
#pragma unroll
            for (int nt = 0; nt < 4; ++nt)
                acc[mt][nt] = __builtin_amdgcn_mfma_f32_16x16x32_bf16(af[mt], bf[nt], acc[mt][nt], 0, 0, 0);
    }

#pragma unroll
    for (int mt = 0; mt < 4; ++mt)
#pragma unroll
        for (int nt = 0; nt < 4; ++nt)
#pragma unroll
            for (int r = 0; r < 4; ++r) {
                long row = m0 + wm + mt * 16 + quad * 4 + r;
                long col = n0 + wn + nt * 16 + lanelo;
                if constexpr (CF) ((float*)Cp)[row * N + col] = acc[mt][nt][r];
                else              ((u16*)Cp)[row * N + col] = f2bf(acc[mt][nt][r]);
            }
}

// ---------- ba = hs @ w_ba (2048x64) with g/beta epilogue ----------
__global__ __launch_bounds__(256) void ba_kernel(const float* __restrict__ hs,
                                                 const float* __restrict__ wba,
                                                 const float* __restrict__ A_log,
                                                 const float* __restrict__ dt_bias,
                                                 float* __restrict__ gbuf,
                                                 float* __restrict__ bbuf)
{
    const int m = blockIdx.x * 4 + (threadIdx.x >> 6);
    const int n = threadIdx.x & 63;
    const float* hrow = &hs[(long)m * 2048];
    float acc = 0.f;
#pragma unroll 8
    for (int k = 0; k < 2048; ++k)
        acc += hrow[k] * wba[(long)k * 64 + n];
    const int hk4 = n >> 2, r = n & 3;
    if (r < 2) {
        bbuf[(long)m * 32 + hk4 * 2 + r] = 1.f / (1.f + expf(-acc));
    } else {
        const int hv = hk4 * 2 + (r - 2);
        float x = acc + dt_bias[hv];
        float sp = (x > 20.f) ? x : log1pf(expf(x));
        gbuf[(long)m * 32 + hv] = -expf(A_log[hv]) * sp;
    }
}

// ---------- causal depthwise conv (K=4) + silu + per-head l2norm, 8 ch/thread ----------
__global__ __launch_bounds__(256) void conv_kernel(const u16* __restrict__ qkvz,
                                                   const float* __restrict__ cw,
                                                   u16* __restrict__ out)
{
    const int bid = blockIdx.x;          // bs*4 + part
    const int bs = bid >> 2, part = bid & 3;
    const int c = part * 2048 + threadIdx.x * 8;
    int n;
    if (c < 2048)       n = (c >> 7) * 768 + (c & 127);
    else if (c < 4096) { int c2 = c - 2048; n = (c2 >> 7) * 768 + 128 + (c2 & 127); }
    else               { int c2 = c - 4096; n = (c2 >> 8) * 768 + 256 + (c2 & 255); }
    const int s = bs & 2047;
    const long base = (long)bs * 12288 + n;

    float x0[8], x1[8], x2[8], x3[8];
#pragma unroll
    for (int i = 0; i < 8; ++i) { x0[i] = 0.f; x1[i] = 0.f; x2[i] = 0.f; }
    { uint4 r = *(const uint4*)&qkvz[base]; unpack8(r, x3); }
    if (s >= 1) { uint4 r = *(const uint4*)&qkvz[base - 12288];     unpack8(r, x2); }
    if (s >= 2) { uint4 r = *(const uint4*)&qkvz[base - 2 * 12288]; unpack8(r, x1); }
    if (s >= 3) { uint4 r = *(const uint4*)&qkvz[base - 3 * 12288]; unpack8(r, x0); }

    float v[8]; float ss = 0.f;
#pragma unroll
    for (int i = 0; i < 8; ++i) {
        float4 w = *(const float4*)&cw[(c + i) * 4];
        float a = x0[i] * w.x + x1[i] * w.y + x2[i] * w.z + x3[i] * w.w;
        v[i] = a / (1.f + expf(-a));
        ss += v[i] * v[i];
    }
    if (part < 2) {   // q/k: l2norm over 128-ch head = 16 consecutive lanes
        ss = row16_allreduce(ss);
        float rn = rsqrtf(ss + 1e-6f);
#pragma unroll
        for (int i = 0; i < 8; ++i) v[i] *= rn;
    }
    uint4 o = make_uint4(pack2(v[0], v[1]), pack2(v[2], v[3]), pack2(v[4], v[5]), pack2(v[6], v[7]));
    *(uint4*)&out[(long)bs * 8192 + c] = o;
}

// ---------- sequential gated delta scan ----------
// grid 512 = (b, h, col-block of 16); 256 threads; lane: rg=lane&15 (8 rows each),
// cloc=wave*4+(lane>>4). State S[8] fp32 in VGPRs. k/q/v staged bf16 via
// global_load_lds; cross-lane reduces via DPP (VALU), not LDS shuffles.
__global__ __launch_bounds__(256) void scan_kernel(const u16* __restrict__ conv,
                                                   const float* __restrict__ gbuf,
                                                   const float* __restrict__ bbuf,
                                                   u16* __restrict__ obuf)
{
    __shared__ __align__(16) u16 lq16[32 * 128];
    __shared__ __align__(16) u16 lk16[32 * 128];
    __shared__ __align__(16) u16 lv16[32 * 16];
    __shared__ float leg[32];
    __shared__ float lbe[32];

    const int bid = blockIdx.x;
    const int b = bid >> 8;
    const int h = (bid >> 3) & 31;
    const int cb = bid & 7;
    const int c0 = cb * 16;
    const int hk = h >> 1;
    const int tid = threadIdx.x;
    const int lane = tid & 63;
    const int rg = lane & 15;
    const int cloc = (tid >> 6) * 4 + (lane >> 4);
    const long rowbase = (long)b * 2048;
    const float scale = 0.08838834764831845f;  // 128^-0.5

    float S[8];
#pragma unroll
    for (int i = 0; i < 8; ++i) S[i] = 0.f;

    for (int t0 = 0; t0 < 2048; t0 += 32) {
        __syncthreads();
        // stage q,k raw bf16: 512 uint4 each, direct global->LDS
        {
            const int tt = tid >> 4, u4 = tid & 15;
            const long base = (rowbase + t0 + tt) * 8192;
            async16(&conv[base + hk * 128 + u4 * 8], &lq16[tid * 8]);
            async16(&conv[base + 2048 + hk * 128 + u4 * 8], &lk16[tid * 8]);
        }
        {
            const int id = tid + 256;
            const int tt = id >> 4, u4 = id & 15;
            const long base = (rowbase + t0 + tt) * 8192;
            async16(&conv[base + hk * 128 + u4 * 8], &lq16[id * 8]);
            async16(&conv[base + 2048 + hk * 128 + u4 * 8], &lk16[id * 8]);
        }
        if (tid < 64) {
            const int tt = tid >> 1, c8 = (tid & 1) * 8;
            async16(&conv[(rowbase + t0 + tt) * 8192 + 4096 + h * 128 + c0 + c8], &lv16[tid * 8]);
        }
        if (tid < 32) {
            leg[tid] = expf(gbuf[(rowbase + t0 + tid) * 32 + h]);
            lbe[tid] = bbuf[(rowbase + t0 + tid) * 32 + h];
        }
        __syncthreads();

        float kr[2][8], qr[2][8], vvp[2], egp[2], bep[2];
        {
            uint4 kw = *(const uint4*)&lk16[rg * 8];
            uint4 qw = *(const uint4*)&lq16[rg * 8];
            unpack8(kw, kr[0]); unpack8(qw, qr[0]);
            vvp[0] = bf2f(lv16[cloc]); egp[0] = leg[0]; bep[0] = lbe[0];
        }
#pragma unroll
        for (int tt = 0; tt < 32; ++tt) {
            const int cur = tt & 1, nxt = cur ^ 1;
            if (tt < 31) {  // prefetch + unpack t+1 while computing t
                uint4 kw = *(const uint4*)&lk16[(tt + 1) * 128 + rg * 8];
                uint4 qw = *(const uint4*)&lq16[(tt + 1) * 128 + rg * 8];
                unpack8(kw, kr[nxt]); unpack8(qw, qr[nxt]);
                vvp[nxt] = bf2f(lv16[(tt + 1) * 16 + cloc]);
                egp[nxt] = leg[tt + 1];
                bep[nxt] = lbe[tt + 1];
            }
            const float eg = egp[cur], be = bep[cur], vv = vvp[cur];
            const float* k8 = kr[cur];
            const float* q8 = qr[cur];
            float pp0 = k8[0] * S[0];
            pp0 = fmaf(k8[2], S[2], pp0); pp0 = fmaf(k8[4], S[4], pp0); pp0 = fmaf(k8[6], S[6], pp0);
            float pp1 = k8[1] * S[1];
            pp1 = fmaf(k8[3], S[3], pp1); pp1 = fmaf(k8[5], S[5], pp1); pp1 = fmaf(k8[7], S[7], pp1);
            float pp = row16_allreduce(pp0 + pp1);
            const float delta = be * (vv - pp * eg);
#pragma unroll
            for (int r = 0; r < 8; ++r) {
                float t = k8[r] * delta;
                S[r] = fmaf(S[r], eg, t);
            }
            float oo0 = q8[0] * S[0];
            oo0 = fmaf(q8[2], S[2], oo0); oo0 = fmaf(q8[4], S[4], oo0); oo0 = fmaf(q8[6], S[6], oo0);
            float oo1 = q8[1] * S[1];
            oo1 = fmaf(q8[3], S[3], oo1); oo1 = fmaf(q8[5], S[5], oo1); oo1 = fmaf(q8[7], S[7], oo1);
            float oo = row16_allreduce(oo0 + oo1);
            if (rg == 0)
                obuf[((rowbase + t0 + tt) * 32 + h) * 128 + c0 + cloc] = f2bf(oo * scale);
        }
    }
}

// ---------- RMS-norm + gating: y = o*rsqrt(mean(o^2)+eps) * norm_w * silu(z) ----------
__global__ __launch_bounds__(128) void gate_kernel(const u16* __restrict__ obuf,
                                                   const u16* __restrict__ qkvz,
                                                   const float* __restrict__ norm_w,
                                                   u16* __restrict__ ybuf)
{
    const int bid = blockIdx.x;          // bs*32 + hv
    const int bs = bid >> 5, hv = bid & 31;
    const int dv = threadIdx.x;
    __shared__ float red[2];
    float v = bf2f(obuf[(long)bid * 128 + dv]);
    float ss = v * v;
    ss += __shfl_xor(ss, 1);  ss += __shfl_xor(ss, 2);  ss += __shfl_xor(ss, 4);
    ss += __shfl_xor(ss, 8);  ss += __shfl_xor(ss, 16); ss += __shfl_xor(ss, 32);
    if ((dv & 63) == 0) red[dv >> 6] = ss;
    __syncthreads();
    const float mean = (red[0] + red[1]) * (1.f / 128.f);
    const float rstd = rsqrtf(mean + 1e-6f);
    const int hk = hv >> 1;
    const float z = bf2f(qkvz[(long)bs * 12288 + hk * 768 + 512 + (hv & 1) * 128 + dv]);
    const float y = v * rstd * norm_w[dv] * (z / (1.f + expf(-z)));
    ybuf[(long)bs * 4096 + hv * 128 + dv] = f2bf(y);
}

// ---------- launch ----------
extern "C" void kernel_launch(void* const* d_in, const int* in_sizes, int n_in,
                              void* d_out, int out_size, void* d_ws, size_t ws_size,
                              hipStream_t stream)
{
    const float* hs      = (const float*)d_in[0];
    const float* w_qkvz  = (const float*)d_in[1];
    const float* w_ba    = (const float*)d_in[2];
    const float* conv_w  = (const float*)d_in[3];
    const float* A_log   = (const float*)d_in[4];
    const float* dt_bias = (const float*)d_in[5];
    const float* norm_w  = (const float*)d_in[6];
    const float* w_out   = (const float*)d_in[7];

    char* ws = (char*)d_ws;
    u16*   qkvz   = (u16*)ws;                          // 100,663,296 B
    u16*   convb  = (u16*)(ws + 100663296);            //  67,108,864 B
    float* gbuf   = (float*)(ws + 167772160);          //     524,288 B
    float* bbuf   = (float*)(ws + 168296448);          //     524,288 B
    char*  regE   = ws + 168820736;                    //  33,554,432 B (end 202,375,168)
    u16*   hs_b   = (u16*)regE;                        // bf16 hs (dead after GEMM1)
    u16*   obuf   = (u16*)regE;                        // overwrites hs_b at scan time
    u16*   wqkvz_t = convb;                            // bf16 w_qkvz^T (dead after GEMM1; conv overwrites)
    u16*   ybuf   = convb;                             // gate output (conv data dead after scan)
    u16*   wout_t = qkvz;                              // bf16 w_out^T (qkvz dead after gate)

    // 1) dtype prep
    f2b_kernel<<<4096, 256, 0, stream>>>(hs, hs_b);                            // 4096*2048
    transpose_f2b<<<dim3(384, 64), 256, 0, stream>>>(w_qkvz, wqkvz_t, 2048, 12288);
    // 2) qkvz = hs @ w_qkvz  (4096 x 12288 x 2048), bf16 out
    gemm_bt<0><<<dim3(96, 32), 256, 0, stream>>>(hs_b, wqkvz_t, qkvz, 4096, 12288, 2048);
    // 3) g/beta
    ba_kernel<<<1024, 256, 0, stream>>>(hs, w_ba, A_log, dt_bias, gbuf, bbuf);
    // 4) conv + silu + l2norm (overwrites wqkvz_t region)
    conv_kernel<<<4096 * 4, 256, 0, stream>>>(qkvz, conv_w, convb);
    // 5) gated delta scan (overwrites hs_b region)
    scan_kernel<<<512, 256, 0, stream>>>(convb, gbuf, bbuf, obuf);
    // 6) gating (writes ybuf = convb region)
    gate_kernel<<<4096 * 32, 128, 0, stream>>>(obuf, qkvz, norm_w, ybuf);
    // 7) w_out^T into qkvz region (dead), then out = y @ w_out (4096 x 2048 x 4096), fp32 out
    transpose_f2b<<<dim3(64, 128), 256, 0, stream>>>(w_out, wout_t, 4096, 2048);
    gemm_bt<1><<<dim3(16, 32), 256, 0, stream>>>(ybuf, wout_t, d_out, 4096, 2048, 4096);
}